// Round 13
// baseline (76.894 us; speedup 1.0000x reference)
//
#include <hip/hip_runtime.h>
#include <hip/hip_bf16.h>
#include <stdint.h>

#define N_VOX 65536
#define NK 27
#define BR 64          // rows per block

typedef float f32x4  __attribute__((ext_vector_type(4)));
typedef int   i32x2  __attribute__((ext_vector_type(2)));
typedef unsigned short u16x2 __attribute__((ext_vector_type(2)));
typedef __bf16 bf16x8 __attribute__((ext_vector_type(8)));

#define WAITVM(n) asm volatile("s_waitcnt vmcnt(" #n ")" ::: "memory")

__device__ __forceinline__ void barrier_fence() {
    asm volatile("" ::: "memory");
    __builtin_amdgcn_s_barrier();
    asm volatile("" ::: "memory");
}

// async global->LDS, 16B per lane; LDS dest = M0 + lane*16 (wave-uniform M0)
__device__ __forceinline__ void gll16(const void* src, uint32_t lds_addr) {
    asm volatile("s_mov_b32 m0, %0\n\t"
                 "global_load_lds_dwordx4 %1, off"
                 :: "s"(lds_addr), "v"(src)
                 : "memory");
}

// W[k][c][d] f32 -> Wt pre-swizzled bf16 so a LINEAR 1KB-per-wave global_load_lds
// produces the XOR-swizzled LDS image directly (inverse-swz source + swz read).
__device__ __forceinline__ void wconv_elem(const float* __restrict__ W,
                                           __bf16* __restrict__ Wt, int Dc, int i) {
    int d = i % Dc;                 // output channel = B row
    int c = (i / Dc) % 64;          // input channel  = B col (K)
    int k = i / (Dc * 64);
    int off = ((d * 128 + ((c >> 3) << 4)) ^ ((d & 7) << 4)) + (c & 7) * 2;
    *(__bf16*)((char*)Wt + (size_t)k * Dc * 128 + off) = (__bf16)W[i];
}

// Fused prep: x f32->bf16 (2048) | W1 (432) | W2 (432) | W3 (108) | zero page (1)
#define PREP_CVT   2048
#define PREP_W1    432
#define PREP_W2    432
#define PREP_W3    108
#define PREP_GRID  (PREP_CVT + PREP_W1 + PREP_W2 + PREP_W3 + 1)
__global__ __launch_bounds__(256) void prep_kernel(
    const float* __restrict__ x,
    const float* __restrict__ W1, const float* __restrict__ W2, const float* __restrict__ W3,
    __bf16* __restrict__ xb, __bf16* __restrict__ Wt1, __bf16* __restrict__ Wt2,
    __bf16* __restrict__ Wt3, float* __restrict__ zp)
{
    const int b = blockIdx.x, tid = threadIdx.x;
    if (b < PREP_CVT) {
        int i = b * 256 + tid;                      // 8 elems/thread, covers N*64
        const f32x4* xp = (const f32x4*)x;
        f32x4 f0 = xp[i * 2], f1 = xp[i * 2 + 1];
        bf16x8 v;
#pragma unroll
        for (int j = 0; j < 4; ++j) { v[j] = (__bf16)f0[j]; v[4 + j] = (__bf16)f1[j]; }
        ((bf16x8*)xb)[i] = v;
    } else if (b < PREP_CVT + PREP_W1) {
        wconv_elem(W1, Wt1, 64, (b - PREP_CVT) * 256 + tid);
    } else if (b < PREP_CVT + PREP_W1 + PREP_W2) {
        wconv_elem(W2, Wt2, 64, (b - PREP_CVT - PREP_W1) * 256 + tid);
    } else if (b < PREP_CVT + PREP_W1 + PREP_W2 + PREP_W3) {
        wconv_elem(W3, Wt3, 16, (b - PREP_CVT - PREP_W1 - PREP_W2) * 256 + tid);
    } else {
        if (tid < 16) ((f32x4*)zp)[tid] = (f32x4){0.f, 0.f, 0.f, 0.f};  // 256B zero page
    }
}

// CH layer (64->64): triple-buffered LDS, ONE barrier per k, prefetch distance 2.
// snid is u16 RAW index (all 0..65535 valid); validity in per-k 64-bit masks
// (2 u32 words) built via LDS atomicOr — no sentinel collision (R12 bug fix).
// Per-iter VMEM tail = exactly 4 wave-uniform ops; WAITVM(4) retires tile k.
__global__ __launch_bounds__(256, 3) void conv_ch(
    const __bf16* __restrict__ feat,      // [N,64] bf16
    const int* __restrict__ nidx,         // [N,27]
    const __bf16* __restrict__ Wt,        // [27][64*64] pre-swizzled bf16
    const float* __restrict__ bias,       // [64]
    __bf16* __restrict__ dst,             // [N,64]
    const __bf16* __restrict__ zp)        // 256B zero page
{
    constexpr int ABSZ = BR * 128;        // 8K A tile (8 x 1KB chunks)
    constexpr int BSZ  = 64 * 128;        // 8K B tile
    constexpr int BOFF = 3 * ABSZ;        // 24K
    constexpr int SNOFF = BOFF + 3 * BSZ; // 48K
    constexpr int VMOFF = SNOFF + NK * 64 * 2;            // u16 slab 3456B
    __shared__ __align__(16) char lds[VMOFF + NK * 2 * 4 + 40];  // ~51.6K -> 3 blk/CU

    const int tid = threadIdx.x;
    const int lane = tid & 63;
    const int wid = tid >> 6;
    const int wr = wid >> 1;              // 0..1 (32-row half)
    const int wc = wid & 1;               // 0..1 (32-col half)
    const int col = lane & 15;
    const int kgrp = lane >> 4;
    const int row0 = blockIdx.x * BR;

    uint16_t* snid = (uint16_t*)(lds + SNOFF);
    unsigned* vm = (unsigned*)(lds + VMOFF);   // vm[k*2 + w]: rows w*32..w*32+31

    // ---- init masks, then preload slab (permuted) + build validity masks ----
    if (tid < NK * 2) vm[tid] = 0u;
    __syncthreads();
    const int* gnid = nidx + (size_t)row0 * NK;
    for (int i = tid; i < BR * NK; i += 256) {
        int r = i / NK;
        int kk = i - r * NK;
        int m = gnid[i];
        snid[kk * 64 + (r & 7) * 8 + (r >> 3)] = (uint16_t)m;   // raw low 16 bits
        if (m >= 0) atomicOr(&vm[kk * 2 + (r >> 5)], 1u << (r & 31));
    }
    __syncthreads();

    const uint32_t ldsbase = (uint32_t)(uintptr_t)(&lds[0]);
    const int qA = ((lane & 7) ^ (lane >> 3)) << 4;  // lane-constant inv-swizzle byte off
    const char* featB = (const char*)feat;
    const char* zpB = (const char*)zp;
    const int vbit0 = (wid & 1) * 16 + (lane >> 3);  // bit for j=0; j=1 adds 8

    // exactly 4 gll16 per wave per k: 2 B chunks + 2 A chunks (chunk c = wid*2+j)
    auto issueK = [&](int k, int wb) {
#pragma unroll
        for (int j = 0; j < 2; ++j) {
            int jb = wid * 2 + j;
            gll16(Wt + (size_t)k * 4096 + jb * 512 + lane * 8,
                  (uint32_t)__builtin_amdgcn_readfirstlane(
                      (int)(ldsbase + BOFF + wb * BSZ + jb * 1024)));
        }
        u16x2 mv = *(const u16x2*)(snid + k * 64 + (lane >> 3) * 8 + wid * 2);
        unsigned w = vm[k * 2 + (wid >> 1)];          // wave-uniform word
#pragma unroll
        for (int j = 0; j < 2; ++j) {
            bool valid = (w >> (vbit0 + j * 8)) & 1u;
            const char* src = valid ? (featB + (size_t)(unsigned)mv[j] * 128 + qA) : zpB;
            gll16(src, (uint32_t)__builtin_amdgcn_readfirstlane(
                           (int)(ldsbase + wb * ABSZ + (wid * 2 + j) * 1024)));
        }
    };

    f32x4 acc[2][2];
#pragma unroll
    for (int mi = 0; mi < 2; ++mi)
#pragma unroll
        for (int ni = 0; ni < 2; ++ni)
#pragma unroll
            for (int j = 0; j < 4; ++j) acc[mi][ni][j] = 0.f;

    auto compute = [&](int bs) {
        const char* Ac = lds + bs * ABSZ;
        const char* Bc = lds + BOFF + bs * BSZ;
        bf16x8 a[2][2], b[2][2];
#pragma unroll
        for (int mi = 0; mi < 2; ++mi) {
            int ar = wr * 32 + mi * 16 + col;
#pragma unroll
            for (int kk = 0; kk < 2; ++kk)
                a[mi][kk] = *(const bf16x8*)(Ac + ((ar * 128 + kk * 64 + kgrp * 16)
                                                   ^ ((ar & 7) << 4)));
        }
#pragma unroll
        for (int ni = 0; ni < 2; ++ni) {
            int br = wc * 32 + ni * 16 + col;
#pragma unroll
            for (int kk = 0; kk < 2; ++kk)
                b[ni][kk] = *(const bf16x8*)(Bc + ((br * 128 + kk * 64 + kgrp * 16)
                                                   ^ ((br & 7) << 4)));
        }
#pragma unroll
        for (int kk = 0; kk < 2; ++kk)
#pragma unroll
            for (int mi = 0; mi < 2; ++mi)
#pragma unroll
                for (int ni = 0; ni < 2; ++ni)
                    acc[mi][ni] = __builtin_amdgcn_mfma_f32_16x16x32_bf16(
                        a[mi][kk], b[ni][kk], acc[mi][ni], 0, 0, 0);
    };

    // ---- prologue: tiles 0 and 1 in flight (8 ops/wave) ----
    issueK(0, 0);
    issueK(1, 1);

    int bs = 0, wb = 2;                   // bs = k%3, wb = (k+2)%3
    for (int k = 0; k < NK; ++k) {
        if (k < NK - 1) { WAITVM(4); }    // retire own tile-k ops; k+1[,k+2] in flight
        else { WAITVM(0); }
        barrier_fence();                  // all waves' tile-k chunks landed
        if (k + 2 < NK) issueK(k + 2, wb);   // overwrites buf[(k-1)%3]: readers done
        compute(bs);
        if (++bs == 3) bs = 0;
        if (++wb == 3) wb = 0;
    }

    // ---- epilogue: C/D layout col=lane&15, row=(lane>>4)*4+reg; bias+relu ----
#pragma unroll
    for (int ni = 0; ni < 2; ++ni) {
        int c = wc * 32 + ni * 16 + col;
        float bv = bias[c];
#pragma unroll
        for (int mi = 0; mi < 2; ++mi) {
#pragma unroll
            for (int reg = 0; reg < 4; ++reg) {
                int r = row0 + wr * 32 + mi * 16 + kgrp * 4 + reg;
                float v = fmaxf(acc[mi][ni][reg] + bv, 0.f);
                dst[(size_t)r * 64 + c] = (__bf16)v;
            }
        }
    }
}

// Layer 3 (64->16, f32 out): R9-proven 4-wave BR=64 double-buffer kernel, unchanged.
__global__ __launch_bounds__(256, 4) void conv_l3(
    const __bf16* __restrict__ feat, const int* __restrict__ nidx,
    const __bf16* __restrict__ Wt, const float* __restrict__ bias,
    float* __restrict__ dst, const __bf16* __restrict__ zp)
{
    constexpr int ABSZ = 64 * 128;              // 8K
    constexpr int BSZ = 16 * 128;               // 2K
    constexpr int BOFF = 2 * ABSZ;
    constexpr int SNOFF = BOFF + 2 * BSZ;
    __shared__ __align__(16) char lds[SNOFF + 64 * NK * 4];

    const int tid = threadIdx.x;
    const int lane = tid & 63;
    const int wid = tid >> 6;
    const int col = lane & 15;
    const int kgrp = lane >> 4;
    const int row0 = blockIdx.x * 64;

    int* snid = (int*)(lds + SNOFF);
    const int* gnid = nidx + (size_t)row0 * NK;
    for (int i = tid; i < 64 * NK; i += 256) {
        int r = i / NK;
        int kk = i - r * NK;
        snid[kk * 64 + (r & 7) * 8 + (r >> 3)] = gnid[i];
    }
    __syncthreads();

    const uint32_t ldsbase = (uint32_t)(uintptr_t)(&lds[0]);
    const int qA = ((lane & 7) ^ (lane >> 3)) << 4;

    auto issueB = [&](int k, int buf) {
        if (wid < 2)
            gll16(Wt + (size_t)k * 1024 + wid * 512 + lane * 8,
                  (uint32_t)__builtin_amdgcn_readfirstlane(
                      (int)(ldsbase + BOFF + buf * BSZ + wid * 1024)));
    };
    auto issueA = [&](int k, int buf) {
        i32x2 mv = *(const i32x2*)(snid + k * 64 + (lane >> 3) * 8 + wid * 2);
#pragma unroll
        for (int j = 0; j < 2; ++j) {
            int m = mv[j];
            const __bf16* src = (m >= 0)
                ? (const __bf16*)((const char*)feat + (size_t)m * 128 + qA) : zp;
            gll16(src, (uint32_t)__builtin_amdgcn_readfirstlane(
                           (int)(ldsbase + buf * ABSZ + (wid * 2 + j) * 1024)));
        }
    };

    f32x4 acc;
#pragma unroll
    for (int j = 0; j < 4; ++j) acc[j] = 0.f;

    auto compute = [&](int k) {
        const char* Ac = lds + (k & 1) * ABSZ;
        const char* Bc = lds + BOFF + (k & 1) * BSZ;
        int ar = wid * 16 + col;
        bf16x8 a[2], b[2];
#pragma unroll
        for (int kk = 0; kk < 2; ++kk) {
            a[kk] = *(const bf16x8*)(Ac + ((ar * 128 + kk * 64 + kgrp * 16)
                                           ^ ((ar & 7) << 4)));
            b[kk] = *(const bf16x8*)(Bc + ((col * 128 + kk * 64 + kgrp * 16)
                                           ^ ((col & 7) << 4)));
        }
#pragma unroll
        for (int kk = 0; kk < 2; ++kk)
            acc = __builtin_amdgcn_mfma_f32_16x16x32_bf16(a[kk], b[kk], acc, 0, 0, 0);
    };

    issueB(0, 0);
    issueA(0, 0);
    for (int k = 0; k < NK; ++k) {
        const int buf = k & 1;
        barrier_fence();
        if (k + 1 < NK) {
            issueB(k + 1, buf ^ 1);
            issueA(k + 1, buf ^ 1);
            if (wid < 2) { WAITVM(3); } else { WAITVM(2); }
        } else {
            WAITVM(0);
        }
        barrier_fence();
        compute(k);
    }

    float bv = bias[col];
#pragma unroll
    for (int reg = 0; reg < 4; ++reg) {
        int r = row0 + wid * 16 + kgrp * 4 + reg;
        dst[(size_t)r * 16 + col] = acc[reg] + bv;
    }
}

extern "C" void kernel_launch(void* const* d_in, const int* in_sizes, int n_in,
                              void* d_out, int out_size, void* d_ws, size_t ws_size,
                              hipStream_t stream) {
    const float* x  = (const float*)d_in[0];
    const int* nidx = (const int*)d_in[1];
    const float* W1 = (const float*)d_in[2];
    const float* b1 = (const float*)d_in[3];
    const float* W2 = (const float*)d_in[4];
    const float* b2 = (const float*)d_in[5];
    const float* W3 = (const float*)d_in[6];
    const float* b3 = (const float*)d_in[7];

    // ws: buf0(8MB: xb, later h2) | buf1(8MB: h1) | Wt1 | Wt2 | Wt3 | zeropage
    char* ws = (char*)d_ws;
    __bf16* buf0 = (__bf16*)ws;
    __bf16* buf1 = (__bf16*)(ws + 8388608);
    __bf16* Wt1  = (__bf16*)(ws + 16777216);
    __bf16* Wt2  = Wt1 + 27 * 64 * 64;
    __bf16* Wt3  = Wt2 + 27 * 64 * 64;
    __bf16* zp   = Wt3 + 27 * 16 * 64;   // 256B-aligned

    prep_kernel<<<PREP_GRID, 256, 0, stream>>>(x, W1, W2, W3, buf0, Wt1, Wt2, Wt3, (float*)zp);

    conv_ch<<<N_VOX / BR, 256, 0, stream>>>(buf0, nidx, Wt1, b1, buf1, zp);
    conv_ch<<<N_VOX / BR, 256, 0, stream>>>(buf1, nidx, Wt2, b2, buf0, zp);
    conv_l3<<<N_VOX / 64, 256, 0, stream>>>(buf0, nidx, Wt3, b3, (float*)d_out, zp);
}

// Round 14
// 68.808 us; speedup vs baseline: 1.1175x; 1.1175x over previous
//
#include <hip/hip_runtime.h>
#include <hip/hip_bf16.h>
#include <stdint.h>

#define N_VOX 65536
#define NK 27
#define BR 64          // rows per block

typedef float f32x4 __attribute__((ext_vector_type(4)));
typedef int   i32x2 __attribute__((ext_vector_type(2)));
typedef __bf16 bf16x8 __attribute__((ext_vector_type(8)));

#define WAITVM(n) asm volatile("s_waitcnt vmcnt(" #n ")" ::: "memory")

__device__ __forceinline__ void barrier_fence() {
    asm volatile("" ::: "memory");
    __builtin_amdgcn_s_barrier();
    asm volatile("" ::: "memory");
}

// async global->LDS, 16B per lane; LDS dest = M0 + lane*16 (wave-uniform M0)
__device__ __forceinline__ void gll16(const void* src, uint32_t lds_addr) {
    asm volatile("s_mov_b32 m0, %0\n\t"
                 "global_load_lds_dwordx4 %1, off"
                 :: "s"(lds_addr), "v"(src)
                 : "memory");
}

// W[k][c][d] f32 -> Wt pre-swizzled bf16 so a LINEAR 1KB-per-wave global_load_lds
// produces the XOR-swizzled LDS image directly (inverse-swz source + swz read).
__device__ __forceinline__ void wconv_elem(const float* __restrict__ W,
                                           __bf16* __restrict__ Wt, int Dc, int i) {
    int d = i % Dc;                 // output channel = B row
    int c = (i / Dc) % 64;          // input channel  = B col (K)
    int k = i / (Dc * 64);
    int off = ((d * 128 + ((c >> 3) << 4)) ^ ((d & 7) << 4)) + (c & 7) * 2;
    *(__bf16*)((char*)Wt + (size_t)k * Dc * 128 + off) = (__bf16)W[i];
}

// Fused prep: x f32->bf16 (2048) | W1 (432) | W2 (432) | W3 (108) | zero page (1)
#define PREP_CVT   2048
#define PREP_W1    432
#define PREP_W2    432
#define PREP_W3    108
#define PREP_GRID  (PREP_CVT + PREP_W1 + PREP_W2 + PREP_W3 + 1)
__global__ __launch_bounds__(256) void prep_kernel(
    const float* __restrict__ x,
    const float* __restrict__ W1, const float* __restrict__ W2, const float* __restrict__ W3,
    __bf16* __restrict__ xb, __bf16* __restrict__ Wt1, __bf16* __restrict__ Wt2,
    __bf16* __restrict__ Wt3, float* __restrict__ zp)
{
    const int b = blockIdx.x, tid = threadIdx.x;
    if (b < PREP_CVT) {
        int i = b * 256 + tid;                      // 8 elems/thread, covers N*64
        const f32x4* xp = (const f32x4*)x;
        f32x4 f0 = xp[i * 2], f1 = xp[i * 2 + 1];
        bf16x8 v;
#pragma unroll
        for (int j = 0; j < 4; ++j) { v[j] = (__bf16)f0[j]; v[4 + j] = (__bf16)f1[j]; }
        ((bf16x8*)xb)[i] = v;
    } else if (b < PREP_CVT + PREP_W1) {
        wconv_elem(W1, Wt1, 64, (b - PREP_CVT) * 256 + tid);
    } else if (b < PREP_CVT + PREP_W1 + PREP_W2) {
        wconv_elem(W2, Wt2, 64, (b - PREP_CVT - PREP_W1) * 256 + tid);
    } else if (b < PREP_CVT + PREP_W1 + PREP_W2 + PREP_W3) {
        wconv_elem(W3, Wt3, 16, (b - PREP_CVT - PREP_W1 - PREP_W2) * 256 + tid);
    } else {
        if (tid < 16) ((f32x4*)zp)[tid] = (f32x4){0.f, 0.f, 0.f, 0.f};  // 256B zero page
    }
}

// One layer: out[n,:] = bias + sum_k feat[nbr(n,k)] @ W[k]   (invalid nbr -> 0)
// R9 (best verified): double-buffered gll16 staging, counted vmcnt, 2 barriers/k,
// 2x2 wave grid for CH (B-read dup 2x), permuted snid slab (one ds_read_b64
// per wave-k for gather indices), lane-constant inverse-swizzle source offset.
template <int NCOLS, bool RELU, bool OUT_F32>
__global__ __launch_bounds__(256, 4) void conv_layer(
    const __bf16* __restrict__ feat,      // [N,64] bf16
    const int* __restrict__ nidx,         // [N,27]
    const __bf16* __restrict__ Wt,        // [27][NCOLS*64] pre-swizzled bf16
    const float* __restrict__ bias,       // [NCOLS]
    void* __restrict__ dst,               // [N,NCOLS]
    const __bf16* __restrict__ zp)        // 256B zero page
{
    constexpr int WC = (NCOLS == 64) ? 2 : 1;   // col-split waves
    constexpr int WR = 4 / WC;                  // row-split waves
    constexpr int MI = BR / (WR * 16);          // 2 (CH) or 1 (COUT)
    constexpr int NI = NCOLS / (WC * 16);       // 2 (CH) or 1 (COUT)
    constexpr int ABSZ = BR * 128;              // 8K A tile (8 x 1KB chunks)
    constexpr int BSZ = NCOLS * 128;            // 8K / 2K B tile
    constexpr int BOFF = 2 * ABSZ;              // 16K
    constexpr int SNOFF = BOFF + 2 * BSZ;
    __shared__ __align__(16) char lds[SNOFF + BR * NK * 4];

    const int tid = threadIdx.x;
    const int lane = tid & 63;
    const int wid = tid >> 6;
    const int wr = wid / WC;
    const int wc = wid % WC;
    const int col = lane & 15;
    const int kgrp = lane >> 4;
    const int row0 = blockIdx.x * BR;

    // ---- preload nidx slab, permuted: snid[k*64 + (r&7)*8 + (r>>3)] = nidx[row0+r][k]
    int* snid = (int*)(lds + SNOFF);
    const int* gnid = nidx + (size_t)row0 * NK;
    for (int i = tid; i < BR * NK; i += 256) {
        int r = i / NK;
        int kk = i - r * NK;
        snid[kk * 64 + (r & 7) * 8 + (r >> 3)] = gnid[i];
    }
    __syncthreads();

    const uint32_t ldsbase = (uint32_t)(uintptr_t)(&lds[0]);
    const int qA = ((lane & 7) ^ (lane >> 3)) << 4;  // lane-constant inv-swizzle byte off

    auto issueB = [&](int k, int buf) {
        if constexpr (NCOLS == 64) {
#pragma unroll
            for (int j = 0; j < 2; ++j) {
                int jb = wid * 2 + j;
                gll16(Wt + (size_t)k * 4096 + jb * 512 + lane * 8,
                      (uint32_t)__builtin_amdgcn_readfirstlane(
                          (int)(ldsbase + BOFF + buf * BSZ + jb * 1024)));
            }
        } else {
            if (wid < 2)
                gll16(Wt + (size_t)k * 1024 + wid * 512 + lane * 8,
                      (uint32_t)__builtin_amdgcn_readfirstlane(
                          (int)(ldsbase + BOFF + buf * BSZ + wid * 1024)));
        }
    };

    // wave stages chunks c = wid*2+{0,1} (8 chunks total across 4 waves);
    // chunk c covers rows c*8 + (lane>>3); permuted snid index = (lane>>3)*8 + c
    auto issueA = [&](int k, int buf) {
        i32x2 mv = *(const i32x2*)(snid + k * 64 + (lane >> 3) * 8 + wid * 2);
#pragma unroll
        for (int j = 0; j < 2; ++j) {
            int m = mv[j];
            const __bf16* src = (m >= 0)
                ? (const __bf16*)((const char*)feat + (size_t)m * 128 + qA) : zp;
            gll16(src, (uint32_t)__builtin_amdgcn_readfirstlane(
                           (int)(ldsbase + buf * ABSZ + (wid * 2 + j) * 1024)));
        }
    };

    f32x4 acc[MI][NI];
#pragma unroll
    for (int mi = 0; mi < MI; ++mi)
#pragma unroll
        for (int ni = 0; ni < NI; ++ni)
#pragma unroll
            for (int j = 0; j < 4; ++j) acc[mi][ni][j] = 0.f;

    auto compute = [&](int k) {
        const char* Ac = lds + (k & 1) * ABSZ;
        const char* Bc = lds + BOFF + (k & 1) * BSZ;
        bf16x8 a[MI][2], b[NI][2];
#pragma unroll
        for (int mi = 0; mi < MI; ++mi) {
            int ar = wr * (MI * 16) + mi * 16 + col;
#pragma unroll
            for (int kk = 0; kk < 2; ++kk)
                a[mi][kk] = *(const bf16x8*)(Ac + ((ar * 128 + kk * 64 + kgrp * 16)
                                                   ^ ((ar & 7) << 4)));
        }
#pragma unroll
        for (int ni = 0; ni < NI; ++ni) {
            int br = wc * (NI * 16) + ni * 16 + col;
#pragma unroll
            for (int kk = 0; kk < 2; ++kk)
                b[ni][kk] = *(const bf16x8*)(Bc + ((br * 128 + kk * 64 + kgrp * 16)
                                                   ^ ((br & 7) << 4)));
        }
#pragma unroll
        for (int kk = 0; kk < 2; ++kk)
#pragma unroll
            for (int mi = 0; mi < MI; ++mi)
#pragma unroll
                for (int ni = 0; ni < NI; ++ni)
                    acc[mi][ni] = __builtin_amdgcn_mfma_f32_16x16x32_bf16(
                        a[mi][kk], b[ni][kk], acc[mi][ni], 0, 0, 0);
    };

    issueB(0, 0);
    issueA(0, 0);

    for (int k = 0; k < NK; ++k) {
        const int buf = k & 1;
        barrier_fence();                    // readers of buf^1 are done
        if (k + 1 < NK) {
            issueB(k + 1, buf ^ 1);
            issueA(k + 1, buf ^ 1);
            // retire own k-ops (2B+2A for CH); own (k+1)-ops stay in flight
            if constexpr (NCOLS == 64) { WAITVM(4); }
            else { if (wid < 2) { WAITVM(3); } else { WAITVM(2); } }
        } else {
            WAITVM(0);
        }
        barrier_fence();                    // all waves' k-tiles landed
        compute(k);
    }

    // ---- epilogue: C/D layout col=lane&15, row=(lane>>4)*4+reg ----
#pragma unroll
    for (int ni = 0; ni < NI; ++ni) {
        int c = wc * (NI * 16) + ni * 16 + col;
        float bv = bias[c];
#pragma unroll
        for (int mi = 0; mi < MI; ++mi) {
#pragma unroll
            for (int reg = 0; reg < 4; ++reg) {
                int r = row0 + wr * (MI * 16) + mi * 16 + kgrp * 4 + reg;
                float v = acc[mi][ni][reg] + bv;
                if (RELU) v = fmaxf(v, 0.f);
                if (OUT_F32) ((float*)dst)[(size_t)r * NCOLS + c] = v;
                else ((__bf16*)dst)[(size_t)r * NCOLS + c] = (__bf16)v;
            }
        }
    }
}

extern "C" void kernel_launch(void* const* d_in, const int* in_sizes, int n_in,
                              void* d_out, int out_size, void* d_ws, size_t ws_size,
                              hipStream_t stream) {
    const float* x  = (const float*)d_in[0];
    const int* nidx = (const int*)d_in[1];
    const float* W1 = (const float*)d_in[2];
    const float* b1 = (const float*)d_in[3];
    const float* W2 = (const float*)d_in[4];
    const float* b2 = (const float*)d_in[5];
    const float* W3 = (const float*)d_in[6];
    const float* b3 = (const float*)d_in[7];

    // ws: buf0(8MB: xb, later h2) | buf1(8MB: h1) | Wt1 | Wt2 | Wt3 | zeropage
    char* ws = (char*)d_ws;
    __bf16* buf0 = (__bf16*)ws;
    __bf16* buf1 = (__bf16*)(ws + 8388608);
    __bf16* Wt1  = (__bf16*)(ws + 16777216);
    __bf16* Wt2  = Wt1 + 27 * 64 * 64;
    __bf16* Wt3  = Wt2 + 27 * 64 * 64;
    __bf16* zp   = Wt3 + 27 * 16 * 64;   // 256B-aligned

    prep_kernel<<<PREP_GRID, 256, 0, stream>>>(x, W1, W2, W3, buf0, Wt1, Wt2, Wt3, (float*)zp);

    dim3 grid(N_VOX / BR);
    conv_layer<64, true,  false><<<grid, 256, 0, stream>>>(buf0, nidx, Wt1, b1, buf1, zp);
    conv_layer<64, true,  false><<<grid, 256, 0, stream>>>(buf1, nidx, Wt2, b2, buf0, zp);
    conv_layer<16, false, true ><<<grid, 256, 0, stream>>>(buf0, nidx, Wt3, b3, d_out, zp);
}